// Round 3
// baseline (482.028 us; speedup 1.0000x reference)
//
#include <hip/hip_runtime.h>
#include <hip/hip_bf16.h>

#define B_    4
#define C_    64
#define H_    192
#define W_    192
#define TAPS_ 9
#define MID_  12
#define HW_   (H_ * W_)
#define K_TOT 576                      // C_ * TAPS_
#define AT_STRIDE 72                   // bf16 elems per a_T row (64 + 8 pad, 16B-aligned)
#define AT_ROWS   200                  // w + t in [0, 200)

constexpr float STD_ = 0.47140452079103173f;  // sqrt(2)/3

using bf16 = __hip_bfloat16;
typedef __attribute__((ext_vector_type(4))) float  f32x4;
typedef __attribute__((ext_vector_type(8))) short  short8;

__device__ __forceinline__ unsigned short f2bf_bits(float v) {
    union { bf16 h; unsigned short u; } cv;
    cv.h = __float2bfloat16(v);   // RNE
    return cv.u;
}

// ---------------------------------------------------------------------------
// k_prep: w2 f32 [o][c][t] -> bf16 ws layout [o][q] with q = t*64 + c.
// ---------------------------------------------------------------------------
__global__ __launch_bounds__(256) void k_prep(const float* __restrict__ w2,
                                              unsigned short* __restrict__ w2bf) {
    int d = blockIdx.x * 256 + threadIdx.x;          // dest index, 36864 total
    int o = d / K_TOT;
    int rem = d - o * K_TOT;
    int t = rem >> 6;
    int c = rem & 63;
    float v = w2[(o * C_ + c) * TAPS_ + t];
    w2bf[d] = f2bf_bits(v);
}

// ---------------------------------------------------------------------------
// k_mean: partial sums of x rows. 768 blocks = 256 (b,c) x 3 parts.
// ---------------------------------------------------------------------------
__global__ __launch_bounds__(256) void k_mean(const float* __restrict__ x,
                                              float* __restrict__ partials) {
    int bx = blockIdx.x;
    int bc = bx / 3, part = bx - 3 * (bx / 3);
    const float4* p = (const float4*)(x + (size_t)bc * HW_ + part * 12288);
    float s = 0.f;
    #pragma unroll
    for (int k = 0; k < 12; ++k) {
        float4 u = p[threadIdx.x + k * 256];
        s += u.x + u.y + u.z + u.w;
    }
    #pragma unroll
    for (int off = 32; off; off >>= 1) s += __shfl_down(s, off);
    __shared__ float red[4];
    if ((threadIdx.x & 63) == 0) red[threadIdx.x >> 6] = s;
    __syncthreads();
    if (threadIdx.x == 0)
        partials[bx] = red[0] + red[1] + red[2] + red[3];
}

// ---------------------------------------------------------------------------
// k_cf: reduce partials -> g; channel branch; FilterNorm -> cfn (B,C,9) f32.
// ---------------------------------------------------------------------------
__global__ __launch_bounds__(256) void k_cf(const float* __restrict__ partials,
                                            const float* __restrict__ cw1,
                                            const float* __restrict__ cb1,
                                            const float* __restrict__ cw2,
                                            const float* __restrict__ cb2,
                                            float* __restrict__ cfn) {
    __shared__ float g_l[B_ * C_];
    __shared__ float h1_l[B_ * MID_];
    int tid = threadIdx.x;
    g_l[tid] = (partials[tid * 3] + partials[tid * 3 + 1] + partials[tid * 3 + 2])
               * (1.0f / HW_);
    __syncthreads();
    if (tid < B_ * MID_) {
        int b = tid / MID_, m = tid % MID_;
        float acc = cb1[m];
        for (int c = 0; c < C_; ++c) acc += g_l[b * C_ + c] * cw1[m * C_ + c];
        h1_l[tid] = fmaxf(acc, 0.f);
    }
    __syncthreads();
    int b = tid >> 6, c = tid & 63;
    float f[TAPS_];
    float mean = 0.f;
    #pragma unroll
    for (int t = 0; t < TAPS_; ++t) {
        int n = c * TAPS_ + t;
        float acc = cb2[n];
        #pragma unroll
        for (int m = 0; m < MID_; ++m) acc += h1_l[b * MID_ + m] * cw2[n * MID_ + m];
        f[t] = acc;
        mean += acc;
    }
    mean *= (1.f / TAPS_);
    float var = 0.f;
    #pragma unroll
    for (int t = 0; t < TAPS_; ++t) { float d = f[t] - mean; var += d * d; }
    var *= (1.f / (TAPS_ - 1));
    float scale = STD_ / (sqrtf(fmaxf(var, 0.f)) + 1e-10f);
    #pragma unroll
    for (int t = 0; t < TAPS_; ++t)
        cfn[(b * C_ + c) * TAPS_ + t] = (f[t] - mean) * scale;
}

// ---------------------------------------------------------------------------
// k_main: one block per (b,h) row. Phases:
//   A: s[9][192] spatial filters (FilterNorm over taps)
//   B: a_T[w+4][c] = bf16(leaky(DDF apply))   (sliding 3x3 window, 2 ch/thread)
//   C: 1x9 conv as bf16 MFMA GEMM M=64(o) x N=192(w) x K=576(t*64+c),
//      A-frags from global w2bf (L2-resident), B-frags ds_read_b128 from a_T.
// ---------------------------------------------------------------------------
__global__ __launch_bounds__(256, 4) void k_main(const float* __restrict__ x,
                                                 const float* __restrict__ sw,
                                                 const float* __restrict__ sb,
                                                 const float* __restrict__ cfn,
                                                 const unsigned short* __restrict__ w2bf,
                                                 const float* __restrict__ bias2,
                                                 float* __restrict__ out) {
    __shared__ __align__(16) char smem[38336];
    short*    aT   = (short*)smem;                 // 200*72*2 = 28800 B
    unsigned* aT32 = (unsigned*)smem;              // same region, uint view
    float*    sw_l = (float*)smem;                 // alias (phase A only), 2304 B
    float*    s_l  = (float*)(smem + 28800);       // 9*192*4 = 6912 B
    float*    cf_l = (float*)(smem + 35712);       // 64*9*4  = 2304 B
    float*    b2_l = (float*)(smem + 38016);       // 256 B
    float*    sb_l = (float*)(smem + 38272);       // 36 B

    int bh = blockIdx.x;
    int bb = bh / H_;
    int h  = bh - bb * H_;
    int tid = threadIdx.x;

    // ---- stage small tables ----
    for (int i = tid; i < TAPS_ * C_; i += 256) sw_l[i] = sw[i];
    for (int i = tid; i < C_ * TAPS_; i += 256) cf_l[i] = cfn[bb * C_ * TAPS_ + i];
    if (tid < C_) b2_l[tid] = bias2[tid];
    if (tid < TAPS_) sb_l[tid] = sb[tid];
    __syncthreads();

    // ---- Phase A: spatial filters ----
    if (tid < W_) {
        int w = tid;
        float acc[TAPS_];
        #pragma unroll
        for (int t = 0; t < TAPS_; ++t) acc[t] = sb_l[t];
        const float* px = x + (size_t)bb * C_ * HW_ + h * W_ + w;
        #pragma unroll 4
        for (int c = 0; c < C_; ++c) {
            float xv = px[(size_t)c * HW_];
            #pragma unroll
            for (int t = 0; t < TAPS_; ++t) acc[t] = fmaf(xv, sw_l[t * C_ + c], acc[t]);
        }
        float mean = 0.f;
        #pragma unroll
        for (int t = 0; t < TAPS_; ++t) mean += acc[t];
        mean *= (1.f / TAPS_);
        float var = 0.f;
        #pragma unroll
        for (int t = 0; t < TAPS_; ++t) { float d = acc[t] - mean; var += d * d; }
        var *= (1.f / (TAPS_ - 1));
        float scale = STD_ / (sqrtf(fmaxf(var, 0.f)) + 1e-10f);
        #pragma unroll
        for (int t = 0; t < TAPS_; ++t) s_l[t * W_ + w] = (acc[t] - mean) * scale;
    }
    __syncthreads();   // phase B overwrites sw_l alias (aT) and reads s_l

    // ---- zero a_T pad rows (0..3 and 196..199) ----
    for (int i = tid; i < 8 * (AT_STRIDE / 2); i += 256) {
        int rowIdx = i / (AT_STRIDE / 2);
        int col    = i - rowIdx * (AT_STRIDE / 2);
        int r = (rowIdx < 4) ? rowIdx : (192 + rowIdx);
        aT32[r * (AT_STRIDE / 2) + col] = 0u;
    }

    // ---- Phase B: DDF apply + leaky -> a_T bf16 ----
    {
        int c2 = tid >> 3;         // 0..31 (channel pair)
        int wg = tid & 7;          // 0..7  (24-wide w block)
        int ca = 2 * c2;
        float cfa[TAPS_], cfb[TAPS_];
        #pragma unroll
        for (int t = 0; t < TAPS_; ++t) {
            cfa[t] = cf_l[ca * TAPS_ + t];
            cfb[t] = cf_l[(ca + 1) * TAPS_ + t];
        }
        const float* xpa = x + ((size_t)bb * C_ + ca) * HW_;
        const float* xpb = xpa + HW_;
        int hm = h - 1, hp = h + 1;
        int vm = (hm >= 0), vp = (hp < H_);
        int rowoff[3] = { hm * W_, h * W_, hp * W_ };
        int rowok[3]  = { vm, 1, vp };

        float A0[3], A1[3], A2[3], Bm0[3], Bm1[3], Bm2[3];
        int s = (3 * c2) % 24;     // visit-order rotation: spreads LDS write banks
        #pragma unroll 1
        for (int jj = 0; jj < 24; ++jj) {
            int j = jj + s; if (j >= 24) j -= 24;
            int w = wg * 24 + j;
            if (jj == 0 || j == 0) {   // (re)prime window at run starts
                #pragma unroll
                for (int r = 0; r < 3; ++r) {
                    int okm = rowok[r] && (w - 1 >= 0);
                    A0[r]  = okm ? xpa[rowoff[r] + w - 1] : 0.f;
                    Bm0[r] = okm ? xpb[rowoff[r] + w - 1] : 0.f;
                    A1[r]  = rowok[r] ? xpa[rowoff[r] + w] : 0.f;
                    Bm1[r] = rowok[r] ? xpb[rowoff[r] + w] : 0.f;
                }
            }
            #pragma unroll
            for (int r = 0; r < 3; ++r) {
                int okp = rowok[r] && (w + 1 < W_);
                A2[r]  = okp ? xpa[rowoff[r] + w + 1] : 0.f;
                Bm2[r] = okp ? xpb[rowoff[r] + w + 1] : 0.f;
            }
            float acc0 = 0.f, acc1 = 0.f;
            #pragma unroll
            for (int t = 0; t < TAPS_; ++t) {
                int r = t / 3, dc = t % 3;
                float st = s_l[t * W_ + w];
                float xa = (dc == 0) ? A0[r] : (dc == 1) ? A1[r] : A2[r];
                float xb = (dc == 0) ? Bm0[r] : (dc == 1) ? Bm1[r] : Bm2[r];
                acc0 = fmaf(xa * st, cfa[t], acc0);
                acc1 = fmaf(xb * st, cfb[t], acc1);
            }
            acc0 = (acc0 >= 0.f) ? acc0 : 0.1f * acc0;
            acc1 = (acc1 >= 0.f) ? acc1 : 0.1f * acc1;
            unsigned pack = ((unsigned)f2bf_bits(acc1) << 16) | (unsigned)f2bf_bits(acc0);
            aT32[(w + 4) * (AT_STRIDE / 2) + c2] = pack;
            #pragma unroll
            for (int r = 0; r < 3; ++r) {
                A0[r] = A1[r]; A1[r] = A2[r];
                Bm0[r] = Bm1[r]; Bm1[r] = Bm2[r];
            }
        }
    }
    __syncthreads();

    // ---- Phase C: MFMA GEMM out[o][w] += A[o][q] * B[q][w], q = t*64 + c ----
    {
        int lane = tid & 63, wid = tid >> 6;
        int quad = lane >> 4, l16 = lane & 15;
        int obase = wid * 16;

        f32x4 acc[12];
        #pragma unroll
        for (int n = 0; n < 12; ++n) acc[n] = (f32x4){0.f, 0.f, 0.f, 0.f};

        const short* w2s = (const short*)w2bf;
        const short* arow = w2s + (obase + l16) * K_TOT + quad * 8;

        #pragma unroll 2
        for (int kk = 0; kk < 18; ++kk) {
            short8 af = *(const short8*)(arow + kk * 32);
            int t = kk >> 1;
            int cstart = ((kk & 1) << 5) + (quad << 3);
            const short* bb8 = aT + (l16 + t) * AT_STRIDE + cstart;
            #pragma unroll
            for (int n = 0; n < 12; ++n) {
                short8 bf = *(const short8*)(bb8 + n * 16 * AT_STRIDE);
                acc[n] = __builtin_amdgcn_mfma_f32_16x16x32_bf16(af, bf, acc[n], 0, 0, 0);
            }
        }

        // epilogue: bias + residual add, C/D layout col=lane&15, row=quad*4+reg
        size_t xbase = (size_t)bb * C_ * HW_ + (size_t)h * W_;
        #pragma unroll
        for (int n = 0; n < 12; ++n) {
            int w = n * 16 + l16;
            #pragma unroll
            for (int reg = 0; reg < 4; ++reg) {
                int o = obase + quad * 4 + reg;
                size_t idx = xbase + (size_t)o * HW_ + w;
                out[idx] = acc[n][reg] + b2_l[o] + x[idx];
            }
        }
    }
}

// ---------------------------------------------------------------------------
extern "C" void kernel_launch(void* const* d_in, const int* in_sizes, int n_in,
                              void* d_out, int out_size, void* d_ws, size_t ws_size,
                              hipStream_t stream) {
    const float* x   = (const float*)d_in[0];
    const float* sw  = (const float*)d_in[1];
    const float* sb  = (const float*)d_in[2];
    const float* cw1 = (const float*)d_in[3];
    const float* cb1 = (const float*)d_in[4];
    const float* cw2 = (const float*)d_in[5];
    const float* cb2 = (const float*)d_in[6];
    const float* w2  = (const float*)d_in[7];
    const float* b2  = (const float*)d_in[8];
    float* out = (float*)d_out;

    unsigned short* w2bf = (unsigned short*)d_ws;                 // 73728 B
    float* partials = (float*)((char*)d_ws + 73728);              // 3072 B
    float* cfn      = (float*)((char*)d_ws + 76800);              // 9216 B

    hipLaunchKernelGGL(k_prep, dim3(144), dim3(256), 0, stream, w2, w2bf);
    hipLaunchKernelGGL(k_mean, dim3(768), dim3(256), 0, stream, x, partials);
    hipLaunchKernelGGL(k_cf, dim3(1), dim3(256), 0, stream,
                       partials, cw1, cb1, cw2, cb2, cfn);
    hipLaunchKernelGGL(k_main, dim3(B_ * H_), dim3(256), 0, stream,
                       x, sw, sb, cfn, w2bf, b2, out);
}

// Round 4
// 159.086 us; speedup vs baseline: 3.0300x; 3.0300x over previous
//
#include <hip/hip_runtime.h>
#include <hip/hip_bf16.h>

#define B_    4
#define C_    64
#define H_    192
#define W_    192
#define TAPS_ 9
#define MID_  12
#define HW_   (H_ * W_)
#define K_TOT 576                      // C_ * TAPS_
#define AT_STRIDE 72                   // bf16 elems per a_T row (64 + 8 pad, 16B-aligned)
#define AT_ROWS   200                  // w + t in [0, 200)

constexpr float STD_ = 0.47140452079103173f;  // sqrt(2)/3

using bf16 = __hip_bfloat16;
typedef __attribute__((ext_vector_type(4))) float  f32x4;
typedef __attribute__((ext_vector_type(8))) short  short8;

__device__ __forceinline__ unsigned short f2bf_bits(float v) {
    union { bf16 h; unsigned short u; } cv;
    cv.h = __float2bfloat16(v);   // RNE
    return cv.u;
}

// ---------------------------------------------------------------------------
// k_prep: w2 f32 [o][c][t] -> bf16 ws layout [o][q] with q = t*64 + c.
// ---------------------------------------------------------------------------
__global__ __launch_bounds__(256) void k_prep(const float* __restrict__ w2,
                                              unsigned short* __restrict__ w2bf) {
    int d = blockIdx.x * 256 + threadIdx.x;          // dest index, 36864 total
    int o = d / K_TOT;
    int rem = d - o * K_TOT;
    int t = rem >> 6;
    int c = rem & 63;
    float v = w2[(o * C_ + c) * TAPS_ + t];
    w2bf[d] = f2bf_bits(v);
}

// ---------------------------------------------------------------------------
// k_mean: partial sums of x rows. 768 blocks = 256 (b,c) x 3 parts.
// ---------------------------------------------------------------------------
__global__ __launch_bounds__(256) void k_mean(const float* __restrict__ x,
                                              float* __restrict__ partials) {
    int bx = blockIdx.x;
    int bc = bx / 3, part = bx - 3 * (bx / 3);
    const float4* p = (const float4*)(x + (size_t)bc * HW_ + part * 12288);
    float s = 0.f;
    #pragma unroll
    for (int k = 0; k < 12; ++k) {
        float4 u = p[threadIdx.x + k * 256];
        s += u.x + u.y + u.z + u.w;
    }
    #pragma unroll
    for (int off = 32; off; off >>= 1) s += __shfl_down(s, off);
    __shared__ float red[4];
    if ((threadIdx.x & 63) == 0) red[threadIdx.x >> 6] = s;
    __syncthreads();
    if (threadIdx.x == 0)
        partials[bx] = red[0] + red[1] + red[2] + red[3];
}

// ---------------------------------------------------------------------------
// k_cf: reduce partials -> g; channel branch; FilterNorm -> cfn (B,C,9) f32.
// ---------------------------------------------------------------------------
__global__ __launch_bounds__(256) void k_cf(const float* __restrict__ partials,
                                            const float* __restrict__ cw1,
                                            const float* __restrict__ cb1,
                                            const float* __restrict__ cw2,
                                            const float* __restrict__ cb2,
                                            float* __restrict__ cfn) {
    __shared__ float g_l[B_ * C_];
    __shared__ float h1_l[B_ * MID_];
    int tid = threadIdx.x;
    g_l[tid] = (partials[tid * 3] + partials[tid * 3 + 1] + partials[tid * 3 + 2])
               * (1.0f / HW_);
    __syncthreads();
    if (tid < B_ * MID_) {
        int b = tid / MID_, m = tid % MID_;
        float acc = cb1[m];
        for (int c = 0; c < C_; ++c) acc += g_l[b * C_ + c] * cw1[m * C_ + c];
        h1_l[tid] = fmaxf(acc, 0.f);
    }
    __syncthreads();
    int b = tid >> 6, c = tid & 63;
    float f[TAPS_];
    float mean = 0.f;
    #pragma unroll
    for (int t = 0; t < TAPS_; ++t) {
        int n = c * TAPS_ + t;
        float acc = cb2[n];
        #pragma unroll
        for (int m = 0; m < MID_; ++m) acc += h1_l[b * MID_ + m] * cw2[n * MID_ + m];
        f[t] = acc;
        mean += acc;
    }
    mean *= (1.f / TAPS_);
    float var = 0.f;
    #pragma unroll
    for (int t = 0; t < TAPS_; ++t) { float d = f[t] - mean; var += d * d; }
    var *= (1.f / (TAPS_ - 1));
    float scale = STD_ / (sqrtf(fmaxf(var, 0.f)) + 1e-10f);
    #pragma unroll
    for (int t = 0; t < TAPS_; ++t)
        cfn[(b * C_ + c) * TAPS_ + t] = (f[t] - mean) * scale;
}

// ---------------------------------------------------------------------------
// k_main: one block per (b,h) row.
//   A: s[9][192] spatial filters (FilterNorm over taps)
//   B: coalesced per-pixel DDF apply + leaky -> a_T[w+4][c] bf16
//      (consecutive lanes = consecutive w: wave loads are contiguous;
//       LDS write has 8-way bank alias but only 48 stores/thread)
//   C: 1x9 conv as bf16 MFMA GEMM M=64(o) x N=192(w) x K=576(t*64+c),
//      A-frags from global w2bf (L2-resident), B-frags ds_read_b128 from a_T.
// ---------------------------------------------------------------------------
__global__ __launch_bounds__(256, 4) void k_main(const float* __restrict__ x,
                                                 const float* __restrict__ sw,
                                                 const float* __restrict__ sb,
                                                 const float* __restrict__ cfn,
                                                 const unsigned short* __restrict__ w2bf,
                                                 const float* __restrict__ bias2,
                                                 float* __restrict__ out) {
    __shared__ __align__(16) char smem[38336];
    short*          aT   = (short*)smem;           // 200*72*2 = 28800 B
    unsigned short* aT16 = (unsigned short*)smem;
    unsigned*       aT32 = (unsigned*)smem;
    float*          sw_l = (float*)smem;           // alias (phase A only), 2304 B
    float*          s_l  = (float*)(smem + 28800); // 9*192*4 = 6912 B
    float*          cf_l = (float*)(smem + 35712); // 64*9*4  = 2304 B
    float*          b2_l = (float*)(smem + 38016); // 256 B
    float*          sb_l = (float*)(smem + 38272); // 36 B

    int bh = blockIdx.x;
    int bb = bh / H_;
    int h  = bh - bb * H_;
    int tid = threadIdx.x;

    // ---- stage small tables ----
    for (int i = tid; i < TAPS_ * C_; i += 256) sw_l[i] = sw[i];
    for (int i = tid; i < C_ * TAPS_; i += 256) cf_l[i] = cfn[bb * C_ * TAPS_ + i];
    if (tid < C_) b2_l[tid] = bias2[tid];
    if (tid < TAPS_) sb_l[tid] = sb[tid];
    __syncthreads();

    // ---- Phase A: spatial filters ----
    if (tid < W_) {
        int w = tid;
        float acc[TAPS_];
        #pragma unroll
        for (int t = 0; t < TAPS_; ++t) acc[t] = sb_l[t];
        const float* px = x + (size_t)bb * C_ * HW_ + h * W_ + w;
        #pragma unroll 4
        for (int c = 0; c < C_; ++c) {
            float xv = px[(size_t)c * HW_];
            #pragma unroll
            for (int t = 0; t < TAPS_; ++t) acc[t] = fmaf(xv, sw_l[t * C_ + c], acc[t]);
        }
        float mean = 0.f;
        #pragma unroll
        for (int t = 0; t < TAPS_; ++t) mean += acc[t];
        mean *= (1.f / TAPS_);
        float var = 0.f;
        #pragma unroll
        for (int t = 0; t < TAPS_; ++t) { float d = acc[t] - mean; var += d * d; }
        var *= (1.f / (TAPS_ - 1));
        float scale = STD_ / (sqrtf(fmaxf(var, 0.f)) + 1e-10f);
        #pragma unroll
        for (int t = 0; t < TAPS_; ++t) s_l[t * W_ + w] = (acc[t] - mean) * scale;
    }
    __syncthreads();   // phase B overwrites sw_l alias (aT) and reads s_l

    // ---- zero a_T pad rows (0..3 and 196..199) ----
    for (int i = tid; i < 8 * (AT_STRIDE / 2); i += 256) {
        int rowIdx = i / (AT_STRIDE / 2);
        int col    = i - rowIdx * (AT_STRIDE / 2);
        int r = (rowIdx < 4) ? rowIdx : (192 + rowIdx);
        aT32[r * (AT_STRIDE / 2) + col] = 0u;
    }

    // ---- Phase B: coalesced DDF apply + leaky -> a_T bf16 ----
    {
        size_t bbase = (size_t)bb * C_ * HW_;
        int vm = (h - 1 >= 0), vp = (h + 1 < H_);
        #pragma unroll 1
        for (int k = 0; k < 48; ++k) {  // 48*256 = 12288 = 64*192
            int p = tid + k * 256;
            int c = p / W_;
            int w = p - c * W_;
            const float* xc = x + bbase + (size_t)c * HW_ + (size_t)h * W_;
            float acc = 0.f;
            #pragma unroll
            for (int t = 0; t < TAPS_; ++t) {
                int r = t / 3, dc = t % 3;
                int ww = w - 1 + dc;
                int rok = (r == 0) ? vm : (r == 2) ? vp : 1;
                float xv = (rok && ww >= 0 && ww < W_)
                               ? xc[(r - 1) * W_ + ww] : 0.f;
                acc = fmaf(xv * s_l[t * W_ + w], cf_l[c * TAPS_ + t], acc);
            }
            acc = (acc >= 0.f) ? acc : 0.1f * acc;
            aT16[(w + 4) * AT_STRIDE + c] = f2bf_bits(acc);
        }
    }
    __syncthreads();

    // ---- Phase C: MFMA GEMM out[o][w] += A[o][q] * B[q][w], q = t*64 + c ----
    {
        int lane = tid & 63, wid = tid >> 6;
        int quad = lane >> 4, l16 = lane & 15;
        int obase = wid * 16;

        f32x4 acc[12];
        #pragma unroll
        for (int n = 0; n < 12; ++n) acc[n] = (f32x4){0.f, 0.f, 0.f, 0.f};

        const short* w2s = (const short*)w2bf;
        const short* arow = w2s + (obase + l16) * K_TOT + quad * 8;

        #pragma unroll 2
        for (int kk = 0; kk < 18; ++kk) {
            short8 af = *(const short8*)(arow + kk * 32);
            int t = kk >> 1;
            int cstart = ((kk & 1) << 5) + (quad << 3);
            const short* bb8 = aT + (l16 + t) * AT_STRIDE + cstart;
            #pragma unroll
            for (int n = 0; n < 12; ++n) {
                short8 bf = *(const short8*)(bb8 + n * 16 * AT_STRIDE);
                acc[n] = __builtin_amdgcn_mfma_f32_16x16x32_bf16(af, bf, acc[n], 0, 0, 0);
            }
        }

        // epilogue: bias + residual add, C/D layout col=lane&15, row=quad*4+reg
        size_t xbase = (size_t)bb * C_ * HW_ + (size_t)h * W_;
        #pragma unroll
        for (int n = 0; n < 12; ++n) {
            int w = n * 16 + l16;
            #pragma unroll
            for (int reg = 0; reg < 4; ++reg) {
                int o = obase + quad * 4 + reg;
                size_t idx = xbase + (size_t)o * HW_ + w;
                out[idx] = acc[n][reg] + b2_l[o] + x[idx];
            }
        }
    }
}

// ---------------------------------------------------------------------------
extern "C" void kernel_launch(void* const* d_in, const int* in_sizes, int n_in,
                              void* d_out, int out_size, void* d_ws, size_t ws_size,
                              hipStream_t stream) {
    const float* x   = (const float*)d_in[0];
    const float* sw  = (const float*)d_in[1];
    const float* sb  = (const float*)d_in[2];
    const float* cw1 = (const float*)d_in[3];
    const float* cb1 = (const float*)d_in[4];
    const float* cw2 = (const float*)d_in[5];
    const float* cb2 = (const float*)d_in[6];
    const float* w2  = (const float*)d_in[7];
    const float* b2  = (const float*)d_in[8];
    float* out = (float*)d_out;

    unsigned short* w2bf = (unsigned short*)d_ws;                 // 73728 B
    float* partials = (float*)((char*)d_ws + 73728);              // 3072 B
    float* cfn      = (float*)((char*)d_ws + 76800);              // 9216 B

    hipLaunchKernelGGL(k_prep, dim3(144), dim3(256), 0, stream, w2, w2bf);
    hipLaunchKernelGGL(k_mean, dim3(768), dim3(256), 0, stream, x, partials);
    hipLaunchKernelGGL(k_cf, dim3(1), dim3(256), 0, stream,
                       partials, cw1, cb1, cw2, cb2, cfn);
    hipLaunchKernelGGL(k_main, dim3(B_ * H_), dim3(256), 0, stream,
                       x, sw, sb, cfn, w2bf, b2, out);
}

// Round 5
// 149.608 us; speedup vs baseline: 3.2219x; 1.0634x over previous
//
#include <hip/hip_runtime.h>
#include <hip/hip_bf16.h>

#define B_    4
#define C_    64
#define H_    192
#define W_    192
#define TAPS_ 9
#define MID_  12
#define HW_   (H_ * W_)
#define K_TOT 576                      // C_ * TAPS_
#define AT_STRIDE 72                   // bf16 elems per a_T row (64 + 8 pad, 16B-aligned)

constexpr float STD_ = 0.47140452079103173f;  // sqrt(2)/3

using bf16 = __hip_bfloat16;
typedef __attribute__((ext_vector_type(4))) float  f32x4;
typedef __attribute__((ext_vector_type(8))) short  short8;

__device__ __forceinline__ unsigned short f2bf_bits(float v) {
    union { bf16 h; unsigned short u; } cv;
    cv.h = __float2bfloat16(v);   // RNE
    return cv.u;
}

// ---------------------------------------------------------------------------
// k_pre: fused {w2 repack -> bf16 [o][t*64+c]} (blocks 0..143) and
//        {x row partial sums} (blocks 144..911).
// ---------------------------------------------------------------------------
__global__ __launch_bounds__(256) void k_pre(const float* __restrict__ x,
                                             const float* __restrict__ w2,
                                             unsigned short* __restrict__ w2bf,
                                             float* __restrict__ partials) {
    int bx = blockIdx.x;
    if (bx < 144) {
        int d = bx * 256 + threadIdx.x;          // dest index, 36864 total
        int o = d / K_TOT;
        int rem = d - o * K_TOT;
        int t = rem >> 6;
        int c = rem & 63;
        w2bf[d] = f2bf_bits(w2[(o * C_ + c) * TAPS_ + t]);
        return;
    }
    bx -= 144;
    int bc = bx / 3, part = bx - 3 * (bx / 3);
    const float4* p = (const float4*)(x + (size_t)bc * HW_ + part * 12288);
    float s = 0.f;
    #pragma unroll
    for (int k = 0; k < 12; ++k) {
        float4 u = p[threadIdx.x + k * 256];
        s += u.x + u.y + u.z + u.w;
    }
    #pragma unroll
    for (int off = 32; off; off >>= 1) s += __shfl_down(s, off);
    __shared__ float red[4];
    if ((threadIdx.x & 63) == 0) red[threadIdx.x >> 6] = s;
    __syncthreads();
    if (threadIdx.x == 0)
        partials[bx] = red[0] + red[1] + red[2] + red[3];
}

// ---------------------------------------------------------------------------
// k_cf: reduce partials -> g; channel branch; FilterNorm -> cfn (B,C,9) f32.
// ---------------------------------------------------------------------------
__global__ __launch_bounds__(256) void k_cf(const float* __restrict__ partials,
                                            const float* __restrict__ cw1,
                                            const float* __restrict__ cb1,
                                            const float* __restrict__ cw2,
                                            const float* __restrict__ cb2,
                                            float* __restrict__ cfn) {
    __shared__ float g_l[B_ * C_];
    __shared__ float h1_l[B_ * MID_];
    int tid = threadIdx.x;
    g_l[tid] = (partials[tid * 3] + partials[tid * 3 + 1] + partials[tid * 3 + 2])
               * (1.0f / HW_);
    __syncthreads();
    if (tid < B_ * MID_) {
        int b = tid / MID_, m = tid % MID_;
        float acc = cb1[m];
        for (int c = 0; c < C_; ++c) acc += g_l[b * C_ + c] * cw1[m * C_ + c];
        h1_l[tid] = fmaxf(acc, 0.f);
    }
    __syncthreads();
    int b = tid >> 6, c = tid & 63;
    float f[TAPS_];
    float mean = 0.f;
    #pragma unroll
    for (int t = 0; t < TAPS_; ++t) {
        int n = c * TAPS_ + t;
        float acc = cb2[n];
        #pragma unroll
        for (int m = 0; m < MID_; ++m) acc += h1_l[b * MID_ + m] * cw2[n * MID_ + m];
        f[t] = acc;
        mean += acc;
    }
    mean *= (1.f / TAPS_);
    float var = 0.f;
    #pragma unroll
    for (int t = 0; t < TAPS_; ++t) { float d = f[t] - mean; var += d * d; }
    var *= (1.f / (TAPS_ - 1));
    float scale = STD_ / (sqrtf(fmaxf(var, 0.f)) + 1e-10f);
    #pragma unroll
    for (int t = 0; t < TAPS_; ++t)
        cfn[(b * C_ + c) * TAPS_ + t] = (f[t] - mean) * scale;
}

// ---------------------------------------------------------------------------
// k_main: one block per (b,h) row.
//   A: s[w][9] spatial filters (FilterNorm over taps), layout s_l[w][12]
//   B: wave<->16ch, lane<->4 pixels (aligned float4 + 2 clamped edge scalars);
//      s taps hoisted to regs (channel-invariant), cf via scalar loads
//   C: 1x9 conv as bf16 MFMA GEMM M=64(o) x N=192(w) x K=576(t*64+c),
//      A-frags prefetched from global w2bf, B-frags ds_read_b128 from a_T
// ---------------------------------------------------------------------------
__global__ __launch_bounds__(256, 4) void k_main(const float* __restrict__ x,
                                                 const float* __restrict__ sw,
                                                 const float* __restrict__ sb,
                                                 const float* __restrict__ cfn,
                                                 const unsigned short* __restrict__ w2bf,
                                                 const float* __restrict__ bias2,
                                                 float* __restrict__ out) {
    __shared__ __align__(16) char smem[38320];
    short*          aT   = (short*)smem;           // 200*72*2 = 28800 B
    unsigned*       aT32 = (unsigned*)smem;
    float*          sw_l = (float*)smem;           // alias (phase A only), 2304 B
    float*          s_l  = (float*)(smem + 28800); // 192*12*4 = 9216 B
    float*          b2_l = (float*)(smem + 38016); // 256 B
    float*          sb_l = (float*)(smem + 38272); // 40 B

    int bh = blockIdx.x;
    int bb = bh / H_;
    int h  = bh - bb * H_;
    int tid = threadIdx.x;

    // ---- stage small tables ----
    for (int i = tid; i < TAPS_ * C_; i += 256) sw_l[i] = sw[i];
    if (tid < C_) b2_l[tid] = bias2[tid];
    if (tid < TAPS_) sb_l[tid] = sb[tid];
    __syncthreads();

    // ---- Phase A: spatial filters ----
    if (tid < W_) {
        int w = tid;
        float acc[TAPS_];
        #pragma unroll
        for (int t = 0; t < TAPS_; ++t) acc[t] = sb_l[t];
        const float* px = x + (size_t)bb * C_ * HW_ + h * W_ + w;
        #pragma unroll 4
        for (int c = 0; c < C_; ++c) {
            float xv = px[(size_t)c * HW_];
            #pragma unroll
            for (int t = 0; t < TAPS_; ++t) acc[t] = fmaf(xv, sw_l[t * C_ + c], acc[t]);
        }
        float mean = 0.f;
        #pragma unroll
        for (int t = 0; t < TAPS_; ++t) mean += acc[t];
        mean *= (1.f / TAPS_);
        float var = 0.f;
        #pragma unroll
        for (int t = 0; t < TAPS_; ++t) { float d = acc[t] - mean; var += d * d; }
        var *= (1.f / (TAPS_ - 1));
        float scale = STD_ / (sqrtf(fmaxf(var, 0.f)) + 1e-10f);
        float* sp = s_l + w * 12;
        #pragma unroll
        for (int t = 0; t < TAPS_; ++t) sp[t] = (acc[t] - mean) * scale;
    }
    __syncthreads();   // phase B overwrites sw_l alias (aT) and reads s_l

    // ---- zero a_T pad rows (0..3 and 196..199) ----
    for (int i = tid; i < 8 * (AT_STRIDE / 2); i += 256) {
        int rowIdx = i / (AT_STRIDE / 2);
        int col    = i - rowIdx * (AT_STRIDE / 2);
        int r = (rowIdx < 4) ? rowIdx : (192 + rowIdx);
        aT32[r * (AT_STRIDE / 2) + col] = 0u;
    }

    // ---- Phase B: DDF apply + leaky -> a_T bf16 ----
    {
        int lane = tid & 63, wid = tid >> 6;
        int wbase = wid * 16;          // 16 channels per wave
        if (lane < 48) {
            int w0 = 4 * lane;         // 4 consecutive pixels per lane
            float sreg[4][TAPS_];      // channel-invariant: load once
            #pragma unroll
            for (int k = 0; k < 4; ++k) {
                const float* sp = s_l + (w0 + k) * 12;
                #pragma unroll
                for (int t = 0; t < TAPS_; ++t) sreg[k][t] = sp[t];
            }
            bool l0 = (lane == 0), l47 = (lane == 47);
            int rok0 = (h > 0), rok2 = (h < H_ - 1);
            int midx = l0 ? 0 : (w0 - 1);        // clamped edge addresses
            int pidx = l47 ? w0 : (w0 + 4);
            const float* xbase = x + (long)bb * C_ * HW_ + (long)(h - 1) * W_;
            #pragma unroll 1
            for (int i = 0; i < 16; i += 2) {
                int c0 = wbase + i;
                int cu = __builtin_amdgcn_readfirstlane(c0);
                const float* cfp = cfn + bb * (C_ * TAPS_) + cu * TAPS_;
                const float* pc0 = xbase + (long)c0 * HW_;
                const float* pc1 = pc0 + HW_;
                float acc0[4] = {0.f, 0.f, 0.f, 0.f};
                float acc1[4] = {0.f, 0.f, 0.f, 0.f};
                #pragma unroll
                for (int r = 0; r < 3; ++r) {
                    if (r == 0 && !rok0) continue;   // block-uniform branches
                    if (r == 2 && !rok2) continue;
                    const float* p0 = pc0 + r * W_;
                    const float* p1 = pc1 + r * W_;
                    float4 fa = *(const float4*)(p0 + w0);   // 16B aligned
                    float4 fb = *(const float4*)(p1 + w0);
                    float ma = l0 ? 0.f : p0[midx];
                    float mb = l0 ? 0.f : p1[midx];
                    float pa = l47 ? 0.f : p0[pidx];
                    float pb = l47 ? 0.f : p1[pidx];
                    float va[6] = { ma, fa.x, fa.y, fa.z, fa.w, pa };
                    float vb[6] = { mb, fb.x, fb.y, fb.z, fb.w, pb };
                    #pragma unroll
                    for (int dc = 0; dc < 3; ++dc) {
                        int t = r * 3 + dc;
                        float cva = cfp[t];
                        float cvb = cfp[TAPS_ + t];
                        #pragma unroll
                        for (int k = 0; k < 4; ++k) {
                            acc0[k] = fmaf(va[k + dc] * sreg[k][t], cva, acc0[k]);
                            acc1[k] = fmaf(vb[k + dc] * sreg[k][t], cvb, acc1[k]);
                        }
                    }
                }
                #pragma unroll
                for (int k = 0; k < 4; ++k) {
                    float a0 = acc0[k]; a0 = (a0 >= 0.f) ? a0 : 0.1f * a0;
                    float a1 = acc1[k]; a1 = (a1 >= 0.f) ? a1 : 0.1f * a1;
                    unsigned pk = (unsigned)f2bf_bits(a0)
                                | ((unsigned)f2bf_bits(a1) << 16);
                    aT32[(w0 + k + 4) * (AT_STRIDE / 2) + (c0 >> 1)] = pk;
                }
            }
        }
    }
    __syncthreads();

    // ---- Phase C: MFMA GEMM out[o][w] += A[o][q] * B[q][w], q = t*64 + c ----
    {
        int lane = tid & 63, wid = tid >> 6;
        int quad = lane >> 4, l16 = lane & 15;
        int obase = wid * 16;

        f32x4 acc[12];
        #pragma unroll
        for (int n = 0; n < 12; ++n) acc[n] = (f32x4){0.f, 0.f, 0.f, 0.f};

        const short* w2s = (const short*)w2bf;
        const short* arow = w2s + (obase + l16) * K_TOT + quad * 8;

        short8 af = *(const short8*)(arow);
        #pragma unroll 1
        for (int kk = 0; kk < 18; ++kk) {
            short8 afn = af;
            if (kk < 17) afn = *(const short8*)(arow + (kk + 1) * 32);  // prefetch
            int t = kk >> 1;
            int cstart = ((kk & 1) << 5) + (quad << 3);
            const short* bb8 = aT + (l16 + t) * AT_STRIDE + cstart;
            #pragma unroll
            for (int n = 0; n < 12; ++n) {
                short8 bf = *(const short8*)(bb8 + n * 16 * AT_STRIDE);
                acc[n] = __builtin_amdgcn_mfma_f32_16x16x32_bf16(af, bf, acc[n], 0, 0, 0);
            }
            af = afn;
        }

        // epilogue: bias + residual add, C/D layout col=lane&15, row=quad*4+reg
        size_t xbase = (size_t)bb * C_ * HW_ + (size_t)h * W_;
        #pragma unroll
        for (int n = 0; n < 12; ++n) {
            int w = n * 16 + l16;
            #pragma unroll
            for (int reg = 0; reg < 4; ++reg) {
                int o = obase + quad * 4 + reg;
                size_t idx = xbase + (size_t)o * HW_ + w;
                out[idx] = acc[n][reg] + b2_l[o] + x[idx];
            }
        }
    }
}

// ---------------------------------------------------------------------------
extern "C" void kernel_launch(void* const* d_in, const int* in_sizes, int n_in,
                              void* d_out, int out_size, void* d_ws, size_t ws_size,
                              hipStream_t stream) {
    const float* x   = (const float*)d_in[0];
    const float* sw  = (const float*)d_in[1];
    const float* sb  = (const float*)d_in[2];
    const float* cw1 = (const float*)d_in[3];
    const float* cb1 = (const float*)d_in[4];
    const float* cw2 = (const float*)d_in[5];
    const float* cb2 = (const float*)d_in[6];
    const float* w2  = (const float*)d_in[7];
    const float* b2  = (const float*)d_in[8];
    float* out = (float*)d_out;

    unsigned short* w2bf = (unsigned short*)d_ws;                 // 73728 B
    float* partials = (float*)((char*)d_ws + 73728);              // 3072 B
    float* cfn      = (float*)((char*)d_ws + 76800);              // 9216 B

    hipLaunchKernelGGL(k_pre, dim3(912), dim3(256), 0, stream, x, w2, w2bf, partials);
    hipLaunchKernelGGL(k_cf, dim3(1), dim3(256), 0, stream,
                       partials, cw1, cb1, cw2, cb2, cfn);
    hipLaunchKernelGGL(k_main, dim3(B_ * H_), dim3(256), 0, stream,
                       x, sw, sb, cfn, w2bf, b2, out);
}